// Round 6
// baseline (784.439 us; speedup 1.0000x reference)
//
#include <hip/hip_runtime.h>
#include <math.h>

// Shapes (fixed)
#define BB 2
#define HH 16
#define SS 2048
#define DD 1024
#define DK 64
#define BHS (BB*HH*SS)          // 65536
#define QSCALE 0.04508422f      // log2(e)/sqrt(1024): folded into q so softmax uses exp2

typedef short  bf16x8  __attribute__((ext_vector_type(8)));
typedef float  floatx4 __attribute__((ext_vector_type(4)));
typedef unsigned short u16;

#define MFMA(a,b,c) __builtin_amdgcn_mfma_f32_16x16x32_bf16((a),(b),(c),0,0,0)

// hardware packed conversion: dst.lo = bf16(lo), dst.hi = bf16(hi), RNE
__device__ __forceinline__ unsigned cvt_pk_bf16(float lo, float hi) {
    unsigned r;
    asm("v_cvt_pk_bf16_f32 %0, %1, %2" : "=v"(r) : "v"(lo), "v"(hi));
    return r;
}
__device__ __forceinline__ bf16x8 ldfrag(const u16* p) {
    union { uint4 u; bf16x8 b; } c;
    c.u = *(const uint4*)p;
    return c.b;
}
__device__ __forceinline__ void stbf4(u16* p, float4 t) {  // 4xf32 -> 4xbf16, 8B store
    union { unsigned u[2]; uint2 v; } c;
    c.u[0] = cvt_pk_bf16(t.x, t.y);
    c.u[1] = cvt_pk_bf16(t.z, t.w);
    *(uint2*)p = c.v;
}
// 4 f32 -> bf16 at p[0], p[16], p[32], p[48]  (C-fragment col stride 16)
__device__ __forceinline__ void st4s(u16* p, float a, float b, float c, float d) {
    unsigned x = cvt_pk_bf16(a, b), y = cvt_pk_bf16(c, d);
    p[0]  = (u16)x; p[16] = (u16)(x >> 16);
    p[32] = (u16)y; p[48] = (u16)(y >> 16);
}
// 2 f32 -> bf16 at p[0], p[16]
__device__ __forceinline__ void st2s(u16* p, float a, float b) {
    unsigned x = cvt_pk_bf16(a, b);
    p[0]  = (u16)x; p[16] = (u16)(x >> 16);
}

// ---------------------------------------------------------------------------
// Kernel 0: one-shot weight conversion fp32->bf16 (frozen).
// ---------------------------------------------------------------------------
#define WQKV_CHUNKS (192*1024/4)     // 49152 float4 chunks
#define WO_CHUNKS   (1024*1024/4)    // 262144
__global__ __launch_bounds__(256) void convert_w(
    const float* __restrict__ wq, const float* __restrict__ wk,
    const float* __restrict__ wv, const float* __restrict__ wo,
    u16* __restrict__ wqkv, u16* __restrict__ wo_bf)
{
    int i = blockIdx.x * 256 + threadIdx.x;
    if (i < WQKV_CHUNKS) {
        int r = i >> 8;            // row 0..191 (256 float4 per row)
        int c = i & 255;
        const float* src = (r < 64) ? wq : ((r < 128) ? wk : wv);
        float4 t = *(const float4*)(src + (size_t)(r & 63) * DD + c * 4);
        stbf4(wqkv + (size_t)r * DD + c * 4, t);
    } else if (i < WQKV_CHUNKS + WO_CHUNKS) {
        int j = i - WQKV_CHUNKS;
        float4 t = *(const float4*)(wo + (size_t)j * 4);
        stbf4(wo_bf + (size_t)j * 4, t);
    }
}

// ---------------------------------------------------------------------------
// Kernel 1: QKV projection (frozen from the 566 us run).
// ---------------------------------------------------------------------------
__global__ __launch_bounds__(512) void qkv_proj(
    const float* __restrict__ x, const u16* __restrict__ wqkv,
    u16* __restrict__ q, u16* __restrict__ k, u16* __restrict__ vT)
{
    __shared__ __align__(16) u16 Ws[2][192][72];   // 55.3 KB double-buffered
    const int tid  = threadIdx.x;
    const int w    = tid >> 6;
    const int lane = tid & 63;
    const int quad = lane >> 4;
    const int l16  = lane & 15;
    const int rt   = w & 3;
    const int g    = w >> 2;
    const int rowbase = blockIdx.x * 64;
    const float* xr = x + (size_t)(rowbase + rt * 16 + l16) * DD + quad * 8;

    uint4 wreg[3];
    auto wload = [&](int kk) {
#pragma unroll
        for (int it = 0; it < 3; ++it) {
            int li = tid + it * 512;
            int r  = li >> 3, c8 = li & 7;
            wreg[it] = *(const uint4*)(wqkv + (size_t)r * DD + kk * 64 + c8 * 8);
        }
    };
    auto wstore = [&](int p) {
#pragma unroll
        for (int it = 0; it < 3; ++it) {
            int li = tid + it * 512;
            int r  = li >> 3, c8 = li & 7;
            *(uint4*)&Ws[p][r][c8 * 8] = wreg[it];
        }
    };

    float4 xc[4], xn[4];
    auto xload = [&](int kk, float4* d) {
        const float* p = xr + kk * 64;
        d[0] = *(const float4*)(p);
        d[1] = *(const float4*)(p + 4);
        d[2] = *(const float4*)(p + 32);
        d[3] = *(const float4*)(p + 36);
    };

    floatx4 acc[6];
#pragma unroll
    for (int j = 0; j < 6; ++j) acc[j] = (floatx4){0.f,0.f,0.f,0.f};

    wload(0); wstore(0);
    xload(0, xc);
    __syncthreads();

    for (int kk = 0; kk < 16; ++kk) {
        int p = kk & 1;
        if (kk < 15) { wload(kk + 1); xload(kk + 1, xn); }
        union { unsigned u[4]; bf16x8 v; } A0, A1;
        A0.u[0] = cvt_pk_bf16(xc[0].x, xc[0].y);
        A0.u[1] = cvt_pk_bf16(xc[0].z, xc[0].w);
        A0.u[2] = cvt_pk_bf16(xc[1].x, xc[1].y);
        A0.u[3] = cvt_pk_bf16(xc[1].z, xc[1].w);
        A1.u[0] = cvt_pk_bf16(xc[2].x, xc[2].y);
        A1.u[1] = cvt_pk_bf16(xc[2].z, xc[2].w);
        A1.u[2] = cvt_pk_bf16(xc[3].x, xc[3].y);
        A1.u[3] = cvt_pk_bf16(xc[3].z, xc[3].w);
#pragma unroll
        for (int j = 0; j < 6; ++j) {
            int n = g * 6 + j;
            bf16x8 b0 = ldfrag(&Ws[p][n * 16 + l16][quad * 8]);
            bf16x8 b1 = ldfrag(&Ws[p][n * 16 + l16][32 + quad * 8]);
            acc[j] = MFMA(A0.v, b0, acc[j]);
            acc[j] = MFMA(A1.v, b1, acc[j]);
        }
        if (kk < 15) {
            wstore(p ^ 1);
#pragma unroll
            for (int i2 = 0; i2 < 4; ++i2) xc[i2] = xn[i2];
            __syncthreads();
        }
    }

    u16 (*Vbuf)[72] = (u16 (*)[72])&Ws[0][0][0];
#pragma unroll
    for (int rr = 0; rr < 4; ++rr) {
        int rloc = rt * 16 + quad * 4 + rr;
        size_t m = (size_t)(rowbase + rloc);
        if (g == 0) {
            st4s(&q[m * DK + l16], acc[0][rr] * QSCALE, acc[1][rr] * QSCALE,
                                   acc[2][rr] * QSCALE, acc[3][rr] * QSCALE);
            st2s(&k[m * DK + l16], acc[4][rr], acc[5][rr]);
        } else {
            st2s(&k[m * DK + 32 + l16], acc[0][rr], acc[1][rr]);
            st4s(&Vbuf[rloc][l16], acc[2][rr], acc[3][rr],
                                   acc[4][rr], acc[5][rr]);
        }
    }
    __syncthreads();
    {
        const int dk = tid >> 3;
        const int sc = (tid & 7) * 8;
        const int bh = rowbase >> 11;
        const int s0 = rowbase & 2047;
        union { u16 s[8]; uint4 u; } t;
#pragma unroll
        for (int u = 0; u < 8; ++u) t.s[u] = Vbuf[sc + u][dk];
        *(uint4*)(vT + ((size_t)(bh * DK + dk)) * SS + s0 + sc) = t.u;
    }
}

// ---------------------------------------------------------------------------
// Kernel 2: flash attention v3. KVBLK=128 (16 iters), Q hoisted to registers,
// DIRECT global->LDS staging (no held reg arrays -> no spill), lazy softmax
// (per-lane partial sums, shuffles only on rescale / at the end), XCD-
// bijective block swizzle (4 bh per XCD -> K/V L2-resident), tuned pads.
// ---------------------------------------------------------------------------
__global__ __launch_bounds__(256) void flash_attn(
    const u16* __restrict__ q, const u16* __restrict__ k,
    const u16* __restrict__ vT, u16* __restrict__ ao)
{
    __shared__ __align__(16) u16 Ks[128][68];      // [t][dk]   17.4 KB
    __shared__ __align__(16) u16 Vt[64][132];      // [dk][t]   16.9 KB
    __shared__ __align__(16) u16 Ps[4][16][132];   // per-wave P 16.9 KB
    const int tid  = threadIdx.x;
    const int w    = tid >> 6;
    const int lane = tid & 63;
    const int quad = lane >> 4;
    const int l16  = lane & 15;
    // XCD swizzle: L = a + 8*(qt + 32*b); bh = a*4 + b  (bijective, 1024 wgs)
    const int L  = blockIdx.y * 32 + blockIdx.x;
    const int qt = (L >> 3) & 31;
    const int bh = (L & 7) * 4 + (L >> 8);
    const size_t kbase = (size_t)bh * SS * DK;
    const size_t vbase = (size_t)bh * DK * SS;

    // Q fragments: invariant over kt -> registers, once
    const u16* qrow = q + kbase + (size_t)(qt * 64 + w * 16 + l16) * DK;
    const bf16x8 qa0 = ldfrag(qrow + quad * 8);
    const bf16x8 qa1 = ldfrag(qrow + 32 + quad * 8);

    float m_i[4], l_part[4];
    floatx4 acc_o[4];
#pragma unroll
    for (int r = 0; r < 4; ++r) { m_i[r] = -INFINITY; l_part[r] = 0.f; }
#pragma unroll
    for (int n = 0; n < 4; ++n) acc_o[n] = (floatx4){0.f,0.f,0.f,0.f};

    for (int kt = 0; kt < SS / 128; ++kt) {
        // direct staging: K [128t][64dk], V [64dk][128t]  (4+4 uint4/thread)
#pragma unroll
        for (int it = 0; it < 4; ++it) {
            int li = tid + it * 256;
            *(uint4*)&Ks[li >> 3][(li & 7) * 8] =
                *(const uint4*)(k + kbase + (size_t)(kt * 128 + (li >> 3)) * DK
                                + (li & 7) * 8);
        }
#pragma unroll
        for (int it = 0; it < 4; ++it) {
            int li = tid + it * 256;
            *(uint4*)&Vt[li >> 4][(li & 15) * 8] =
                *(const uint4*)(vT + vbase + (size_t)(li >> 4) * SS
                                + kt * 128 + (li & 15) * 8);
        }
        __syncthreads();

        // QK^T (log2 units): 8 n-tiles x 128 keys
        floatx4 sc[8];
        __builtin_amdgcn_s_setprio(1);
#pragma unroll
        for (int n = 0; n < 8; ++n) {
            sc[n] = (floatx4){0.f,0.f,0.f,0.f};
            bf16x8 b0 = ldfrag(&Ks[n * 16 + l16][quad * 8]);
            bf16x8 b1 = ldfrag(&Ks[n * 16 + l16][32 + quad * 8]);
            sc[n] = MFMA(qa0, b0, sc[n]);
            sc[n] = MFMA(qa1, b1, sc[n]);
        }
        __builtin_amdgcn_s_setprio(0);

        // lane-local max check (no shuffles in the common case)
        float lm[4];
#pragma unroll
        for (int r = 0; r < 4; ++r)
            lm[r] = fmaxf(fmaxf(fmaxf(sc[0][r], sc[1][r]), fmaxf(sc[2][r], sc[3][r])),
                          fmaxf(fmaxf(sc[4][r], sc[5][r]), fmaxf(sc[6][r], sc[7][r])));
        int ok = (lm[0] <= m_i[0] + 8.f) & (lm[1] <= m_i[1] + 8.f) &
                 (lm[2] <= m_i[2] + 8.f) & (lm[3] <= m_i[3] + 8.f);
        if (!__all(ok)) {          // rare: full 16-lane reduce + rescale
#pragma unroll
            for (int r = 0; r < 4; ++r) {
                float rm = lm[r];
#pragma unroll
                for (int off = 1; off < 16; off <<= 1)
                    rm = fmaxf(rm, __shfl_xor(rm, off, 64));
                float mnew  = fmaxf(m_i[r], rm);
                float alpha = __builtin_amdgcn_exp2f(m_i[r] - mnew);
#pragma unroll
                for (int n = 0; n < 4; ++n) acc_o[n][r] *= alpha;
                l_part[r] *= alpha;
                m_i[r]     = mnew;
            }
        }
        // P = exp2(S - m); per-lane partial row sums; P -> LDS
#pragma unroll
        for (int r = 0; r < 4; ++r) {
            float mi = m_i[r];
            float p0 = __builtin_amdgcn_exp2f(sc[0][r] - mi);
            float p1 = __builtin_amdgcn_exp2f(sc[1][r] - mi);
            float p2 = __builtin_amdgcn_exp2f(sc[2][r] - mi);
            float p3 = __builtin_amdgcn_exp2f(sc[3][r] - mi);
            float p4 = __builtin_amdgcn_exp2f(sc[4][r] - mi);
            float p5 = __builtin_amdgcn_exp2f(sc[5][r] - mi);
            float p6 = __builtin_amdgcn_exp2f(sc[6][r] - mi);
            float p7 = __builtin_amdgcn_exp2f(sc[7][r] - mi);
            l_part[r] += ((p0 + p1) + (p2 + p3)) + ((p4 + p5) + (p6 + p7));
            st4s(&Ps[w][quad * 4 + r][l16],      p0, p1, p2, p3);
            st4s(&Ps[w][quad * 4 + r][64 + l16], p4, p5, p6, p7);
        }
        // Ps per-wave private: no barrier (compiler inserts lgkmcnt)

        // PV: O += P[16 x 128t] * V[128t x 64dk]
        __builtin_amdgcn_s_setprio(1);
#pragma unroll
        for (int kc = 0; kc < 4; ++kc) {
            bf16x8 a = ldfrag(&Ps[w][l16][kc * 32 + quad * 8]);
#pragma unroll
            for (int n = 0; n < 4; ++n) {
                bf16x8 b = ldfrag(&Vt[n * 16 + l16][kc * 32 + quad * 8]);
                acc_o[n] = MFMA(a, b, acc_o[n]);
            }
        }
        __builtin_amdgcn_s_setprio(0);
        __syncthreads();                           // Ks/Vt consumed
    }

    // epilogue: final 16-lane reduce of l_part, then -> ao[B,S,H*64] bf16
    const int b = bh >> 4, h = bh & 15;
#pragma unroll
    for (int r = 0; r < 4; ++r) {
        float l = l_part[r];
#pragma unroll
        for (int off = 1; off < 16; off <<= 1)
            l += __shfl_xor(l, off, 64);
        float rl = __builtin_amdgcn_rcpf(l);
        int srow = qt * 64 + w * 16 + quad * 4 + r;
        size_t base = ((size_t)(b * SS + srow)) * (HH * DK) + h * 64;
        st4s(&ao[base + l16], acc_o[0][r] * rl, acc_o[1][r] * rl,
                              acc_o[2][r] * rl, acc_o[3][r] * rl);
    }
}

// ---------------------------------------------------------------------------
// Kernel 3: output projection v3. BM=BN=128, BK=64, 512 thr (8 waves),
// wave w owns rows w*16..+15 x all 128 cols -> 16 MFMA / 18 ds_reads per
// k-step. Plain direct staging (no held regs). Grid 256 = 1 block/CU;
// same-nt blocks land on one XCD (L%8 = nt) -> B panel L2-resident.
// ---------------------------------------------------------------------------
__global__ __launch_bounds__(512) void out_proj(
    const u16* __restrict__ ao, const u16* __restrict__ wo_bf,
    float* __restrict__ out)
{
    __shared__ __align__(16) u16 As[128][68];
    __shared__ __align__(16) u16 Bs[128][68];
    const int tid  = threadIdx.x;
    const int w    = tid >> 6;
    const int lane = tid & 63;
    const int quad = lane >> 4;
    const int l16  = lane & 15;
    const int mt = blockIdx.y;     // 0..31
    const int nt = blockIdx.x;     // 0..7

    floatx4 acc[8];
#pragma unroll
    for (int n = 0; n < 8; ++n) acc[n] = (floatx4){0.f,0.f,0.f,0.f};

    for (int kk = 0; kk < 16; ++kk) {
        // stage A,B 128x64 (1024 uint4 each, 2/thread each)
#pragma unroll
        for (int it = 0; it < 2; ++it) {
            int li = tid + it * 512;
            int r  = li >> 3, c8 = li & 7;
            *(uint4*)&As[r][c8 * 8] =
                *(const uint4*)(ao + (size_t)(mt * 128 + r) * DD + kk * 64 + c8 * 8);
            *(uint4*)&Bs[r][c8 * 8] =
                *(const uint4*)(wo_bf + (size_t)(nt * 128 + r) * DD + kk * 64 + c8 * 8);
        }
        __syncthreads();

        bf16x8 a0 = ldfrag(&As[w * 16 + l16][quad * 8]);
        bf16x8 a1 = ldfrag(&As[w * 16 + l16][32 + quad * 8]);
#pragma unroll
        for (int n = 0; n < 8; ++n) {
            bf16x8 b0 = ldfrag(&Bs[n * 16 + l16][quad * 8]);
            bf16x8 b1 = ldfrag(&Bs[n * 16 + l16][32 + quad * 8]);
            acc[n] = MFMA(a0, b0, acc[n]);
            acc[n] = MFMA(a1, b1, acc[n]);
        }
        __syncthreads();
    }

#pragma unroll
    for (int rr = 0; rr < 4; ++rr) {
        int row = mt * 128 + w * 16 + quad * 4 + rr;
#pragma unroll
        for (int n = 0; n < 8; ++n)
            out[(size_t)row * DD + nt * 128 + n * 16 + l16] = acc[n][rr];
    }
}

// ---------------------------------------------------------------------------
extern "C" void kernel_launch(void* const* d_in, const int* in_sizes, int n_in,
                              void* d_out, int out_size, void* d_ws, size_t ws_size,
                              hipStream_t stream) {
    const float* x  = (const float*)d_in[0];
    const float* wq = (const float*)d_in[1];
    const float* wk = (const float*)d_in[2];
    const float* wv = (const float*)d_in[3];
    const float* wo = (const float*)d_in[4];
    float* out = (float*)d_out;

    u16* q     = (u16*)d_ws;
    u16* k     = q    + (size_t)BHS * DK;
    u16* vT    = k    + (size_t)BHS * DK;
    u16* ao    = vT   + (size_t)BHS * DK;
    u16* wqkv  = ao   + (size_t)BHS * DK;
    u16* wo_bf = wqkv + (size_t)192 * DD;

    convert_w<<<dim3((WQKV_CHUNKS + WO_CHUNKS) / 256), dim3(256), 0, stream>>>(
        wq, wk, wv, wo, wqkv, wo_bf);
    qkv_proj<<<dim3(BHS / 64), dim3(512), 0, stream>>>(x, wqkv, q, k, vT);
    flash_attn<<<dim3(32, 32), dim3(256), 0, stream>>>(q, k, vT, ao);
    out_proj<<<dim3(DD / 128, (BB * SS) / 128), dim3(512), 0, stream>>>(ao, wo_bf, out);
}

// Round 7
// 598.098 us; speedup vs baseline: 1.3116x; 1.3116x over previous
//
#include <hip/hip_runtime.h>
#include <math.h>

// Shapes (fixed)
#define BB 2
#define HH 16
#define SS 2048
#define DD 1024
#define DK 64
#define BHS (BB*HH*SS)          // 65536
#define QSCALE 0.04508422f      // log2(e)/sqrt(1024): folded into q so softmax uses exp2

typedef short  bf16x8  __attribute__((ext_vector_type(8)));
typedef float  floatx4 __attribute__((ext_vector_type(4)));
typedef unsigned short u16;

#define MFMA(a,b,c) __builtin_amdgcn_mfma_f32_16x16x32_bf16((a),(b),(c),0,0,0)

// hardware packed conversion: dst.lo = bf16(lo), dst.hi = bf16(hi), RNE
__device__ __forceinline__ unsigned cvt_pk_bf16(float lo, float hi) {
    unsigned r;
    asm("v_cvt_pk_bf16_f32 %0, %1, %2" : "=v"(r) : "v"(lo), "v"(hi));
    return r;
}
__device__ __forceinline__ bf16x8 ldfrag(const u16* p) {
    union { uint4 u; bf16x8 b; } c;
    c.u = *(const uint4*)p;
    return c.b;
}
__device__ __forceinline__ void stbf4(u16* p, float4 t) {  // 4xf32 -> 4xbf16, 8B store
    union { unsigned u[2]; uint2 v; } c;
    c.u[0] = cvt_pk_bf16(t.x, t.y);
    c.u[1] = cvt_pk_bf16(t.z, t.w);
    *(uint2*)p = c.v;
}
// 4 f32 -> bf16 at p[0], p[16], p[32], p[48]  (C-fragment col stride 16)
__device__ __forceinline__ void st4s(u16* p, float a, float b, float c, float d) {
    unsigned x = cvt_pk_bf16(a, b), y = cvt_pk_bf16(c, d);
    p[0]  = (u16)x; p[16] = (u16)(x >> 16);
    p[32] = (u16)y; p[48] = (u16)(y >> 16);
}
// 2 f32 -> bf16 at p[0], p[16]
__device__ __forceinline__ void st2s(u16* p, float a, float b) {
    unsigned x = cvt_pk_bf16(a, b);
    p[0]  = (u16)x; p[16] = (u16)(x >> 16);
}

// ---------------------------------------------------------------------------
// Kernel 0: one-shot weight conversion fp32->bf16 (frozen).
// ---------------------------------------------------------------------------
#define WQKV_CHUNKS (192*1024/4)     // 49152 float4 chunks
#define WO_CHUNKS   (1024*1024/4)    // 262144
__global__ __launch_bounds__(256) void convert_w(
    const float* __restrict__ wq, const float* __restrict__ wk,
    const float* __restrict__ wv, const float* __restrict__ wo,
    u16* __restrict__ wqkv, u16* __restrict__ wo_bf)
{
    int i = blockIdx.x * 256 + threadIdx.x;
    if (i < WQKV_CHUNKS) {
        int r = i >> 8;            // row 0..191 (256 float4 per row)
        int c = i & 255;
        const float* src = (r < 64) ? wq : ((r < 128) ? wk : wv);
        float4 t = *(const float4*)(src + (size_t)(r & 63) * DD + c * 4);
        stbf4(wqkv + (size_t)r * DD + c * 4, t);
    } else if (i < WQKV_CHUNKS + WO_CHUNKS) {
        int j = i - WQKV_CHUNKS;
        float4 t = *(const float4*)(wo + (size_t)j * 4);
        stbf4(wo_bf + (size_t)j * 4, t);
    }
}

// ---------------------------------------------------------------------------
// Kernel 1: QKV projection (frozen from the 566 us run).
// ---------------------------------------------------------------------------
__global__ __launch_bounds__(512) void qkv_proj(
    const float* __restrict__ x, const u16* __restrict__ wqkv,
    u16* __restrict__ q, u16* __restrict__ k, u16* __restrict__ vT)
{
    __shared__ __align__(16) u16 Ws[2][192][72];   // 55.3 KB double-buffered
    const int tid  = threadIdx.x;
    const int w    = tid >> 6;
    const int lane = tid & 63;
    const int quad = lane >> 4;
    const int l16  = lane & 15;
    const int rt   = w & 3;
    const int g    = w >> 2;
    const int rowbase = blockIdx.x * 64;
    const float* xr = x + (size_t)(rowbase + rt * 16 + l16) * DD + quad * 8;

    uint4 wreg[3];
    auto wload = [&](int kk) {
#pragma unroll
        for (int it = 0; it < 3; ++it) {
            int li = tid + it * 512;
            int r  = li >> 3, c8 = li & 7;
            wreg[it] = *(const uint4*)(wqkv + (size_t)r * DD + kk * 64 + c8 * 8);
        }
    };
    auto wstore = [&](int p) {
#pragma unroll
        for (int it = 0; it < 3; ++it) {
            int li = tid + it * 512;
            int r  = li >> 3, c8 = li & 7;
            *(uint4*)&Ws[p][r][c8 * 8] = wreg[it];
        }
    };

    float4 xc[4], xn[4];
    auto xload = [&](int kk, float4* d) {
        const float* p = xr + kk * 64;
        d[0] = *(const float4*)(p);
        d[1] = *(const float4*)(p + 4);
        d[2] = *(const float4*)(p + 32);
        d[3] = *(const float4*)(p + 36);
    };

    floatx4 acc[6];
#pragma unroll
    for (int j = 0; j < 6; ++j) acc[j] = (floatx4){0.f,0.f,0.f,0.f};

    wload(0); wstore(0);
    xload(0, xc);
    __syncthreads();

    for (int kk = 0; kk < 16; ++kk) {
        int p = kk & 1;
        if (kk < 15) { wload(kk + 1); xload(kk + 1, xn); }
        union { unsigned u[4]; bf16x8 v; } A0, A1;
        A0.u[0] = cvt_pk_bf16(xc[0].x, xc[0].y);
        A0.u[1] = cvt_pk_bf16(xc[0].z, xc[0].w);
        A0.u[2] = cvt_pk_bf16(xc[1].x, xc[1].y);
        A0.u[3] = cvt_pk_bf16(xc[1].z, xc[1].w);
        A1.u[0] = cvt_pk_bf16(xc[2].x, xc[2].y);
        A1.u[1] = cvt_pk_bf16(xc[2].z, xc[2].w);
        A1.u[2] = cvt_pk_bf16(xc[3].x, xc[3].y);
        A1.u[3] = cvt_pk_bf16(xc[3].z, xc[3].w);
#pragma unroll
        for (int j = 0; j < 6; ++j) {
            int n = g * 6 + j;
            bf16x8 b0 = ldfrag(&Ws[p][n * 16 + l16][quad * 8]);
            bf16x8 b1 = ldfrag(&Ws[p][n * 16 + l16][32 + quad * 8]);
            acc[j] = MFMA(A0.v, b0, acc[j]);
            acc[j] = MFMA(A1.v, b1, acc[j]);
        }
        if (kk < 15) {
            wstore(p ^ 1);
#pragma unroll
            for (int i2 = 0; i2 < 4; ++i2) xc[i2] = xn[i2];
            __syncthreads();
        }
    }

    u16 (*Vbuf)[72] = (u16 (*)[72])&Ws[0][0][0];
#pragma unroll
    for (int rr = 0; rr < 4; ++rr) {
        int rloc = rt * 16 + quad * 4 + rr;
        size_t m = (size_t)(rowbase + rloc);
        if (g == 0) {
            st4s(&q[m * DK + l16], acc[0][rr] * QSCALE, acc[1][rr] * QSCALE,
                                   acc[2][rr] * QSCALE, acc[3][rr] * QSCALE);
            st2s(&k[m * DK + l16], acc[4][rr], acc[5][rr]);
        } else {
            st2s(&k[m * DK + 32 + l16], acc[0][rr], acc[1][rr]);
            st4s(&Vbuf[rloc][l16], acc[2][rr], acc[3][rr],
                                   acc[4][rr], acc[5][rr]);
        }
    }
    __syncthreads();
    {
        const int dk = tid >> 3;
        const int sc = (tid & 7) * 8;
        const int bh = rowbase >> 11;
        const int s0 = rowbase & 2047;
        union { u16 s[8]; uint4 u; } t;
#pragma unroll
        for (int u = 0; u < 8; ++u) t.s[u] = Vbuf[sc + u][dk];
        *(uint4*)(vT + ((size_t)(bh * DK + dk)) * SS + s0 + sc) = t.u;
    }
}

// ---------------------------------------------------------------------------
// Kernel 2: flash attention — R3-measured structure (KVBLK=64, eager softmax)
// with ONE change: Q fragments hoisted to registers (kt-invariant).
// Deletes the Qs LDS tile (−2 ds_reads/iter; LDS 36.9->27.6 KB -> 5 blk/CU).
// ---------------------------------------------------------------------------
__global__ __launch_bounds__(256) void flash_attn(
    const u16* __restrict__ q, const u16* __restrict__ k,
    const u16* __restrict__ vT, u16* __restrict__ ao)
{
    __shared__ __align__(16) u16 Ks[64][72];
    __shared__ __align__(16) u16 Vt[64][72];       // Vt[dk][t]
    __shared__ __align__(16) u16 Ps[4][16][72];    // per-wave P tile
    const int tid  = threadIdx.x;
    const int w    = tid >> 6;
    const int lane = tid & 63;
    const int quad = lane >> 4;
    const int l16  = lane & 15;
    const int qt   = blockIdx.x;
    const int bh   = blockIdx.y;
    const size_t kbase = (size_t)bh * SS * DK;     // q,k layout [bh*S + t][64]
    const size_t vbase = (size_t)bh * DK * SS;     // vT layout [bh*64 + dk][S]

    // Q fragments: invariant over kt -> registers, once
    const u16* qrow = q + kbase + (size_t)(qt * 64 + w * 16 + l16) * DK;
    const bf16x8 qa0 = ldfrag(qrow + quad * 8);
    const bf16x8 qa1 = ldfrag(qrow + 32 + quad * 8);

    float m_i[4], l_i[4];
    floatx4 acc_o[4];
#pragma unroll
    for (int r = 0; r < 4; ++r) { m_i[r] = -INFINITY; l_i[r] = 0.f; }
#pragma unroll
    for (int n = 0; n < 4; ++n) acc_o[n] = (floatx4){0.f,0.f,0.f,0.f};

    for (int kt = 0; kt < SS / 64; ++kt) {
        // stage K tile [64 t][64 dk] and Vt tile [64 dk][64 t]
#pragma unroll
        for (int it = 0; it < 2; ++it) {
            int li = tid + it * 256;
            int r  = li >> 3, c8 = li & 7;
            *(uint4*)&Ks[r][c8 * 8] =
                *(const uint4*)(k + kbase + (size_t)(kt * 64 + r) * DK + c8 * 8);
            *(uint4*)&Vt[r][c8 * 8] =
                *(const uint4*)(vT + vbase + (size_t)r * SS + kt * 64 + c8 * 8);
        }
        __syncthreads();

        // scores (log2 units)
        floatx4 sc[4];
        __builtin_amdgcn_s_setprio(1);
#pragma unroll
        for (int n = 0; n < 4; ++n) {
            sc[n] = (floatx4){0.f,0.f,0.f,0.f};
            bf16x8 b0 = ldfrag(&Ks[n * 16 + l16][quad * 8]);
            bf16x8 b1 = ldfrag(&Ks[n * 16 + l16][32 + quad * 8]);
            sc[n] = MFMA(qa0, b0, sc[n]);
            sc[n] = MFMA(qa1, b1, sc[n]);
        }
        __builtin_amdgcn_s_setprio(0);

        // row maxima (row = quad*4+r), 16-lane butterfly
        float rmx[4];
#pragma unroll
        for (int r = 0; r < 4; ++r) {
            float rm = fmaxf(fmaxf(sc[0][r], sc[1][r]), fmaxf(sc[2][r], sc[3][r]));
#pragma unroll
            for (int off = 1; off < 16; off <<= 1)
                rm = fmaxf(rm, __shfl_xor(rm, off, 64));
            rmx[r] = rm;
        }
        // defer-max (THR=8 in log2 units)
        int ok = (rmx[0] <= m_i[0] + 8.f) & (rmx[1] <= m_i[1] + 8.f) &
                 (rmx[2] <= m_i[2] + 8.f) & (rmx[3] <= m_i[3] + 8.f);
        if (!__all(ok)) {
#pragma unroll
            for (int r = 0; r < 4; ++r) {
                float mnew  = fmaxf(m_i[r], rmx[r]);
                float alpha = __builtin_amdgcn_exp2f(m_i[r] - mnew);
#pragma unroll
                for (int n = 0; n < 4; ++n) acc_o[n][r] *= alpha;
                l_i[r] *= alpha;
                m_i[r]  = mnew;
            }
        }
        // P = exp2(S - m), row sums, P -> LDS
#pragma unroll
        for (int r = 0; r < 4; ++r) {
            float mi = m_i[r];
            float p0 = __builtin_amdgcn_exp2f(sc[0][r] - mi);
            float p1 = __builtin_amdgcn_exp2f(sc[1][r] - mi);
            float p2 = __builtin_amdgcn_exp2f(sc[2][r] - mi);
            float p3 = __builtin_amdgcn_exp2f(sc[3][r] - mi);
            float rs = (p0 + p1) + (p2 + p3);
#pragma unroll
            for (int off = 1; off < 16; off <<= 1)
                rs += __shfl_xor(rs, off, 64);
            l_i[r] += rs;
            st4s(&Ps[w][quad * 4 + r][l16], p0, p1, p2, p3);
        }
        // Ps per-wave private: no barrier (compiler inserts lgkmcnt)

        // PV
        __builtin_amdgcn_s_setprio(1);
#pragma unroll
        for (int kc = 0; kc < 2; ++kc) {
            bf16x8 a = ldfrag(&Ps[w][l16][kc * 32 + quad * 8]);
#pragma unroll
            for (int n = 0; n < 4; ++n) {
                bf16x8 b = ldfrag(&Vt[n * 16 + l16][kc * 32 + quad * 8]);
                acc_o[n] = MFMA(a, b, acc_o[n]);
            }
        }
        __builtin_amdgcn_s_setprio(0);
        __syncthreads();                            // done reading Ks/Vt
    }

    // epilogue -> ao[B,S,H*64] bf16
    const int b = bh >> 4, h = bh & 15;
#pragma unroll
    for (int r = 0; r < 4; ++r) {
        int srow = qt * 64 + w * 16 + quad * 4 + r;
        float rl = __builtin_amdgcn_rcpf(l_i[r]);
        size_t base = ((size_t)(b * SS + srow)) * (HH * DK) + h * 64;
        st4s(&ao[base + l16], acc_o[0][r] * rl, acc_o[1][r] * rl,
                              acc_o[2][r] * rl, acc_o[3][r] * rl);
    }
}

// ---------------------------------------------------------------------------
// Kernel 3: output projection. BM=128, BN=64, BK=64; 256 thr (4 waves).
// Grid 512 blocks (2+/CU dispatch, 26 KB LDS -> 6 resident): staging overlap
// across blocks. Wave w: rows w*32..+31 x 4 n-tiles -> 16 MFMA / 12 ds_reads
// per k-step. v1 staging structure (no held regs, no clamps).
// Traffic: A 128 MB + B 64 MB (vs v1's 128+128).
// ---------------------------------------------------------------------------
__global__ __launch_bounds__(256) void out_proj(
    const u16* __restrict__ ao, const u16* __restrict__ wo_bf,
    float* __restrict__ out)
{
    __shared__ __align__(16) u16 As[128][68];   // 17.4 KB
    __shared__ __align__(16) u16 Bs[64][68];    //  8.7 KB
    const int tid  = threadIdx.x;
    const int w    = tid >> 6;
    const int lane = tid & 63;
    const int quad = lane >> 4;
    const int l16  = lane & 15;
    const int mt = blockIdx.y;     // 0..31
    const int nt = blockIdx.x;     // 0..15

    floatx4 acc[2][4];
#pragma unroll
    for (int rt = 0; rt < 2; ++rt)
#pragma unroll
        for (int n = 0; n < 4; ++n) acc[rt][n] = (floatx4){0.f,0.f,0.f,0.f};

    for (int kk = 0; kk < 16; ++kk) {
        // stage A 128x64 (1024 uint4, 4/thread) + B 64x64 (512 uint4, 2/thread)
#pragma unroll
        for (int it = 0; it < 4; ++it) {
            int li = tid + it * 256;
            int r  = li >> 3, c8 = li & 7;
            *(uint4*)&As[r][c8 * 8] =
                *(const uint4*)(ao + (size_t)(mt * 128 + r) * DD + kk * 64 + c8 * 8);
        }
#pragma unroll
        for (int it = 0; it < 2; ++it) {
            int li = tid + it * 256;
            int r  = li >> 3, c8 = li & 7;
            *(uint4*)&Bs[r][c8 * 8] =
                *(const uint4*)(wo_bf + (size_t)(nt * 64 + r) * DD + kk * 64 + c8 * 8);
        }
        __syncthreads();

#pragma unroll
        for (int kc = 0; kc < 2; ++kc) {
            bf16x8 a0 = ldfrag(&As[w * 32 + l16][kc * 32 + quad * 8]);
            bf16x8 a1 = ldfrag(&As[w * 32 + 16 + l16][kc * 32 + quad * 8]);
#pragma unroll
            for (int n = 0; n < 4; ++n) {
                bf16x8 b = ldfrag(&Bs[n * 16 + l16][kc * 32 + quad * 8]);
                acc[0][n] = MFMA(a0, b, acc[0][n]);
                acc[1][n] = MFMA(a1, b, acc[1][n]);
            }
        }
        __syncthreads();
    }

#pragma unroll
    for (int rt = 0; rt < 2; ++rt) {
#pragma unroll
        for (int rr = 0; rr < 4; ++rr) {
            int row = mt * 128 + w * 32 + rt * 16 + quad * 4 + rr;
#pragma unroll
            for (int n = 0; n < 4; ++n)
                out[(size_t)row * DD + nt * 64 + n * 16 + l16] = acc[rt][n][rr];
        }
    }
}

// ---------------------------------------------------------------------------
extern "C" void kernel_launch(void* const* d_in, const int* in_sizes, int n_in,
                              void* d_out, int out_size, void* d_ws, size_t ws_size,
                              hipStream_t stream) {
    const float* x  = (const float*)d_in[0];
    const float* wq = (const float*)d_in[1];
    const float* wk = (const float*)d_in[2];
    const float* wv = (const float*)d_in[3];
    const float* wo = (const float*)d_in[4];
    float* out = (float*)d_out;

    u16* q     = (u16*)d_ws;
    u16* k     = q    + (size_t)BHS * DK;
    u16* vT    = k    + (size_t)BHS * DK;
    u16* ao    = vT   + (size_t)BHS * DK;
    u16* wqkv  = ao   + (size_t)BHS * DK;
    u16* wo_bf = wqkv + (size_t)192 * DD;

    convert_w<<<dim3((WQKV_CHUNKS + WO_CHUNKS) / 256), dim3(256), 0, stream>>>(
        wq, wk, wv, wo, wqkv, wo_bf);
    qkv_proj<<<dim3(BHS / 64), dim3(512), 0, stream>>>(x, wqkv, q, k, vT);
    flash_attn<<<dim3(SS / 64, BB * HH), dim3(256), 0, stream>>>(q, k, vT, ao);
    out_proj<<<dim3(DD / 64, (BB * SS) / 128), dim3(256), 0, stream>>>(ao, wo_bf, out);
}

// Round 8
// 556.266 us; speedup vs baseline: 1.4102x; 1.0752x over previous
//
#include <hip/hip_runtime.h>
#include <math.h>

// Shapes (fixed)
#define BB 2
#define HH 16
#define SS 2048
#define DD 1024
#define DK 64
#define BHS (BB*HH*SS)          // 65536
#define QSCALE 0.04508422f      // log2(e)/sqrt(1024): folded into q so softmax uses exp2

typedef short  bf16x8  __attribute__((ext_vector_type(8)));
typedef float  floatx4 __attribute__((ext_vector_type(4)));
typedef unsigned short u16;

#define MFMA(a,b,c) __builtin_amdgcn_mfma_f32_16x16x32_bf16((a),(b),(c),0,0,0)

// hardware packed conversion: dst.lo = bf16(lo), dst.hi = bf16(hi), RNE
__device__ __forceinline__ unsigned cvt_pk_bf16(float lo, float hi) {
    unsigned r;
    asm("v_cvt_pk_bf16_f32 %0, %1, %2" : "=v"(r) : "v"(lo), "v"(hi));
    return r;
}
__device__ __forceinline__ bf16x8 ldfrag(const u16* p) {
    union { uint4 u; bf16x8 b; } c;
    c.u = *(const uint4*)p;
    return c.b;
}
__device__ __forceinline__ void stbf4(u16* p, float4 t) {  // 4xf32 -> 4xbf16, 8B store
    union { unsigned u[2]; uint2 v; } c;
    c.u[0] = cvt_pk_bf16(t.x, t.y);
    c.u[1] = cvt_pk_bf16(t.z, t.w);
    *(uint2*)p = c.v;
}
// 4 f32 -> bf16 at p[0], p[16], p[32], p[48]  (C-fragment col stride 16)
__device__ __forceinline__ void st4s(u16* p, float a, float b, float c, float d) {
    unsigned x = cvt_pk_bf16(a, b), y = cvt_pk_bf16(c, d);
    p[0]  = (u16)x; p[16] = (u16)(x >> 16);
    p[32] = (u16)y; p[48] = (u16)(y >> 16);
}
// 2 f32 -> bf16 at p[0], p[16]
__device__ __forceinline__ void st2s(u16* p, float a, float b) {
    unsigned x = cvt_pk_bf16(a, b);
    p[0]  = (u16)x; p[16] = (u16)(x >> 16);
}

// ---------------------------------------------------------------------------
// Kernel 0: one-shot weight conversion fp32->bf16 (frozen).
// ---------------------------------------------------------------------------
#define WQKV_CHUNKS (192*1024/4)     // 49152 float4 chunks
#define WO_CHUNKS   (1024*1024/4)    // 262144
__global__ __launch_bounds__(256) void convert_w(
    const float* __restrict__ wq, const float* __restrict__ wk,
    const float* __restrict__ wv, const float* __restrict__ wo,
    u16* __restrict__ wqkv, u16* __restrict__ wo_bf)
{
    int i = blockIdx.x * 256 + threadIdx.x;
    if (i < WQKV_CHUNKS) {
        int r = i >> 8;            // row 0..191 (256 float4 per row)
        int c = i & 255;
        const float* src = (r < 64) ? wq : ((r < 128) ? wk : wv);
        float4 t = *(const float4*)(src + (size_t)(r & 63) * DD + c * 4);
        stbf4(wqkv + (size_t)r * DD + c * 4, t);
    } else if (i < WQKV_CHUNKS + WO_CHUNKS) {
        int j = i - WQKV_CHUNKS;
        float4 t = *(const float4*)(wo + (size_t)j * 4);
        stbf4(wo_bf + (size_t)j * 4, t);
    }
}

// ---------------------------------------------------------------------------
// Kernel 1: QKV projection (frozen from the 566 us run).
// ---------------------------------------------------------------------------
__global__ __launch_bounds__(512) void qkv_proj(
    const float* __restrict__ x, const u16* __restrict__ wqkv,
    u16* __restrict__ q, u16* __restrict__ k, u16* __restrict__ vT)
{
    __shared__ __align__(16) u16 Ws[2][192][72];   // 55.3 KB double-buffered
    const int tid  = threadIdx.x;
    const int w    = tid >> 6;
    const int lane = tid & 63;
    const int quad = lane >> 4;
    const int l16  = lane & 15;
    const int rt   = w & 3;
    const int g    = w >> 2;
    const int rowbase = blockIdx.x * 64;
    const float* xr = x + (size_t)(rowbase + rt * 16 + l16) * DD + quad * 8;

    uint4 wreg[3];
    auto wload = [&](int kk) {
#pragma unroll
        for (int it = 0; it < 3; ++it) {
            int li = tid + it * 512;
            int r  = li >> 3, c8 = li & 7;
            wreg[it] = *(const uint4*)(wqkv + (size_t)r * DD + kk * 64 + c8 * 8);
        }
    };
    auto wstore = [&](int p) {
#pragma unroll
        for (int it = 0; it < 3; ++it) {
            int li = tid + it * 512;
            int r  = li >> 3, c8 = li & 7;
            *(uint4*)&Ws[p][r][c8 * 8] = wreg[it];
        }
    };

    float4 xc[4], xn[4];
    auto xload = [&](int kk, float4* d) {
        const float* p = xr + kk * 64;
        d[0] = *(const float4*)(p);
        d[1] = *(const float4*)(p + 4);
        d[2] = *(const float4*)(p + 32);
        d[3] = *(const float4*)(p + 36);
    };

    floatx4 acc[6];
#pragma unroll
    for (int j = 0; j < 6; ++j) acc[j] = (floatx4){0.f,0.f,0.f,0.f};

    wload(0); wstore(0);
    xload(0, xc);
    __syncthreads();

    for (int kk = 0; kk < 16; ++kk) {
        int p = kk & 1;
        if (kk < 15) { wload(kk + 1); xload(kk + 1, xn); }
        union { unsigned u[4]; bf16x8 v; } A0, A1;
        A0.u[0] = cvt_pk_bf16(xc[0].x, xc[0].y);
        A0.u[1] = cvt_pk_bf16(xc[0].z, xc[0].w);
        A0.u[2] = cvt_pk_bf16(xc[1].x, xc[1].y);
        A0.u[3] = cvt_pk_bf16(xc[1].z, xc[1].w);
        A1.u[0] = cvt_pk_bf16(xc[2].x, xc[2].y);
        A1.u[1] = cvt_pk_bf16(xc[2].z, xc[2].w);
        A1.u[2] = cvt_pk_bf16(xc[3].x, xc[3].y);
        A1.u[3] = cvt_pk_bf16(xc[3].z, xc[3].w);
#pragma unroll
        for (int j = 0; j < 6; ++j) {
            int n = g * 6 + j;
            bf16x8 b0 = ldfrag(&Ws[p][n * 16 + l16][quad * 8]);
            bf16x8 b1 = ldfrag(&Ws[p][n * 16 + l16][32 + quad * 8]);
            acc[j] = MFMA(A0.v, b0, acc[j]);
            acc[j] = MFMA(A1.v, b1, acc[j]);
        }
        if (kk < 15) {
            wstore(p ^ 1);
#pragma unroll
            for (int i2 = 0; i2 < 4; ++i2) xc[i2] = xn[i2];
            __syncthreads();
        }
    }

    u16 (*Vbuf)[72] = (u16 (*)[72])&Ws[0][0][0];
#pragma unroll
    for (int rr = 0; rr < 4; ++rr) {
        int rloc = rt * 16 + quad * 4 + rr;
        size_t m = (size_t)(rowbase + rloc);
        if (g == 0) {
            st4s(&q[m * DK + l16], acc[0][rr] * QSCALE, acc[1][rr] * QSCALE,
                                   acc[2][rr] * QSCALE, acc[3][rr] * QSCALE);
            st2s(&k[m * DK + l16], acc[4][rr], acc[5][rr]);
        } else {
            st2s(&k[m * DK + 32 + l16], acc[0][rr], acc[1][rr]);
            st4s(&Vbuf[rloc][l16], acc[2][rr], acc[3][rr],
                                   acc[4][rr], acc[5][rr]);
        }
    }
    __syncthreads();
    {
        const int dk = tid >> 3;
        const int sc = (tid & 7) * 8;
        const int bh = rowbase >> 11;
        const int s0 = rowbase & 2047;
        union { u16 s[8]; uint4 u; } t;
#pragma unroll
        for (int u = 0; u < 8; ++u) t.s[u] = Vbuf[sc + u][dk];
        *(uint4*)(vT + ((size_t)(bh * DK + dk)) * SS + s0 + sc) = t.u;
    }
}

// ---------------------------------------------------------------------------
// Kernel 2: flash attention v4. QBLK=128 via 512 thr / 8 waves: wave w owns
// q-rows (w>>2)*64 + (w&3)*16 .. +15. K/V staged ONCE per 128 q-rows (halves
// per-q-row staging DS-ops and K/V L2/HBM traffic vs QBLK=64) while waves/CU
// stays 16 (2 blocks x 8 waves). Per-wave inner loop identical to the
// measured v1: KVBLK=64, eager softmax + defer-max, P via LDS, setprio.
// Q fragments in registers (kt-invariant).
// ---------------------------------------------------------------------------
__global__ __launch_bounds__(512) void flash_attn(
    const u16* __restrict__ q, const u16* __restrict__ k,
    const u16* __restrict__ vT, u16* __restrict__ ao)
{
    __shared__ __align__(16) u16 Ks[64][72];       //  9.2 KB
    __shared__ __align__(16) u16 Vt[64][72];       //  9.2 KB  Vt[dk][t]
    __shared__ __align__(16) u16 Ps[8][16][72];    // 18.4 KB per-wave P tiles
    const int tid  = threadIdx.x;
    const int w    = tid >> 6;
    const int lane = tid & 63;
    const int quad = lane >> 4;
    const int l16  = lane & 15;
    const int rg   = w >> 2;       // row group (0/1) within 128-row tile
    const int rt   = w & 3;        // row tile within group
    const int qt   = blockIdx.x;   // 0..15
    const int bh   = blockIdx.y;
    const size_t kbase = (size_t)bh * SS * DK;     // q,k layout [bh*S + t][64]
    const size_t vbase = (size_t)bh * DK * SS;     // vT layout [bh*64 + dk][S]

    // Q fragments: invariant over kt -> registers, once
    const u16* qrow = q + kbase +
        (size_t)(qt * 128 + rg * 64 + rt * 16 + l16) * DK;
    const bf16x8 qa0 = ldfrag(qrow + quad * 8);
    const bf16x8 qa1 = ldfrag(qrow + 32 + quad * 8);

    float m_i[4], l_i[4];
    floatx4 acc_o[4];
#pragma unroll
    for (int r = 0; r < 4; ++r) { m_i[r] = -INFINITY; l_i[r] = 0.f; }
#pragma unroll
    for (int n = 0; n < 4; ++n) acc_o[n] = (floatx4){0.f,0.f,0.f,0.f};

    for (int kt = 0; kt < SS / 64; ++kt) {
        // stage K tile [64 t][64 dk] and Vt tile [64 dk][64 t]
        // 512 uint4 chunks each -> exactly 1 K-chunk + 1 V-chunk per thread
        {
            int r  = tid >> 3, c8 = tid & 7;
            *(uint4*)&Ks[r][c8 * 8] =
                *(const uint4*)(k + kbase + (size_t)(kt * 64 + r) * DK + c8 * 8);
            *(uint4*)&Vt[r][c8 * 8] =
                *(const uint4*)(vT + vbase + (size_t)r * SS + kt * 64 + c8 * 8);
        }
        __syncthreads();

        // scores (log2 units)
        floatx4 sc[4];
        __builtin_amdgcn_s_setprio(1);
#pragma unroll
        for (int n = 0; n < 4; ++n) {
            sc[n] = (floatx4){0.f,0.f,0.f,0.f};
            bf16x8 b0 = ldfrag(&Ks[n * 16 + l16][quad * 8]);
            bf16x8 b1 = ldfrag(&Ks[n * 16 + l16][32 + quad * 8]);
            sc[n] = MFMA(qa0, b0, sc[n]);
            sc[n] = MFMA(qa1, b1, sc[n]);
        }
        __builtin_amdgcn_s_setprio(0);

        // row maxima (row = quad*4+r), 16-lane butterfly
        float rmx[4];
#pragma unroll
        for (int r = 0; r < 4; ++r) {
            float rm = fmaxf(fmaxf(sc[0][r], sc[1][r]), fmaxf(sc[2][r], sc[3][r]));
#pragma unroll
            for (int off = 1; off < 16; off <<= 1)
                rm = fmaxf(rm, __shfl_xor(rm, off, 64));
            rmx[r] = rm;
        }
        // defer-max (THR=8 in log2 units)
        int ok = (rmx[0] <= m_i[0] + 8.f) & (rmx[1] <= m_i[1] + 8.f) &
                 (rmx[2] <= m_i[2] + 8.f) & (rmx[3] <= m_i[3] + 8.f);
        if (!__all(ok)) {
#pragma unroll
            for (int r = 0; r < 4; ++r) {
                float mnew  = fmaxf(m_i[r], rmx[r]);
                float alpha = __builtin_amdgcn_exp2f(m_i[r] - mnew);
#pragma unroll
                for (int n = 0; n < 4; ++n) acc_o[n][r] *= alpha;
                l_i[r] *= alpha;
                m_i[r]  = mnew;
            }
        }
        // P = exp2(S - m), row sums, P -> LDS
#pragma unroll
        for (int r = 0; r < 4; ++r) {
            float mi = m_i[r];
            float p0 = __builtin_amdgcn_exp2f(sc[0][r] - mi);
            float p1 = __builtin_amdgcn_exp2f(sc[1][r] - mi);
            float p2 = __builtin_amdgcn_exp2f(sc[2][r] - mi);
            float p3 = __builtin_amdgcn_exp2f(sc[3][r] - mi);
            float rs = (p0 + p1) + (p2 + p3);
#pragma unroll
            for (int off = 1; off < 16; off <<= 1)
                rs += __shfl_xor(rs, off, 64);
            l_i[r] += rs;
            st4s(&Ps[w][quad * 4 + r][l16], p0, p1, p2, p3);
        }
        // Ps per-wave private: no barrier (compiler inserts lgkmcnt)

        // PV
        __builtin_amdgcn_s_setprio(1);
#pragma unroll
        for (int kc = 0; kc < 2; ++kc) {
            bf16x8 a = ldfrag(&Ps[w][l16][kc * 32 + quad * 8]);
#pragma unroll
            for (int n = 0; n < 4; ++n) {
                bf16x8 b = ldfrag(&Vt[n * 16 + l16][kc * 32 + quad * 8]);
                acc_o[n] = MFMA(a, b, acc_o[n]);
            }
        }
        __builtin_amdgcn_s_setprio(0);
        __syncthreads();                            // done reading Ks/Vt
    }

    // epilogue -> ao[B,S,H*64] bf16
    const int b = bh >> 4, h = bh & 15;
#pragma unroll
    for (int r = 0; r < 4; ++r) {
        int srow = qt * 128 + rg * 64 + rt * 16 + quad * 4 + r;
        float rl = __builtin_amdgcn_rcpf(l_i[r]);
        size_t base = ((size_t)(b * SS + srow)) * (HH * DK) + h * 64;
        st4s(&ao[base + l16], acc_o[0][r] * rl, acc_o[1][r] * rl,
                              acc_o[2][r] * rl, acc_o[3][r] * rl);
    }
}

// ---------------------------------------------------------------------------
// Kernel 3: output projection (reverted to the R3-measured v1: 64x64, 256 thr,
// grid 1024 -> 4 blocks/CU staging overlap).
// ---------------------------------------------------------------------------
__global__ __launch_bounds__(256) void out_proj(
    const u16* __restrict__ ao, const u16* __restrict__ wo_bf,
    float* __restrict__ out)
{
    __shared__ __align__(16) u16 As[64][72];
    __shared__ __align__(16) u16 Bs[64][72];
    const int tid  = threadIdx.x;
    const int w    = tid >> 6;
    const int lane = tid & 63;
    const int quad = lane >> 4;
    const int l16  = lane & 15;
    const int mt = blockIdx.y;
    const int nt = blockIdx.x;

    floatx4 acc[4];
#pragma unroll
    for (int n = 0; n < 4; ++n) acc[n] = (floatx4){0.f,0.f,0.f,0.f};

    for (int k0 = 0; k0 < DD; k0 += 64) {
#pragma unroll
        for (int it = 0; it < 2; ++it) {
            int li = tid + it * 256;
            int r  = li >> 3, c8 = li & 7;
            *(uint4*)&As[r][c8 * 8] =
                *(const uint4*)(ao + (size_t)(mt * 64 + r) * DD + k0 + c8 * 8);
            *(uint4*)&Bs[r][c8 * 8] =
                *(const uint4*)(wo_bf + (size_t)(nt * 64 + r) * DD + k0 + c8 * 8);
        }
        __syncthreads();

        bf16x8 a0 = ldfrag(&As[w * 16 + l16][quad * 8]);
        bf16x8 a1 = ldfrag(&As[w * 16 + l16][32 + quad * 8]);
#pragma unroll
        for (int n = 0; n < 4; ++n) {
            bf16x8 b0 = ldfrag(&Bs[n * 16 + l16][quad * 8]);
            bf16x8 b1 = ldfrag(&Bs[n * 16 + l16][32 + quad * 8]);
            acc[n] = MFMA(a0, b0, acc[n]);
            acc[n] = MFMA(a1, b1, acc[n]);
        }
        __syncthreads();
    }

#pragma unroll
    for (int r = 0; r < 4; ++r) {
        int row = mt * 64 + w * 16 + quad * 4 + r;
#pragma unroll
        for (int n = 0; n < 4; ++n)
            out[(size_t)row * DD + nt * 64 + n * 16 + l16] = acc[n][r];
    }
}

// ---------------------------------------------------------------------------
extern "C" void kernel_launch(void* const* d_in, const int* in_sizes, int n_in,
                              void* d_out, int out_size, void* d_ws, size_t ws_size,
                              hipStream_t stream) {
    const float* x  = (const float*)d_in[0];
    const float* wq = (const float*)d_in[1];
    const float* wk = (const float*)d_in[2];
    const float* wv = (const float*)d_in[3];
    const float* wo = (const float*)d_in[4];
    float* out = (float*)d_out;

    u16* q     = (u16*)d_ws;
    u16* k     = q    + (size_t)BHS * DK;
    u16* vT    = k    + (size_t)BHS * DK;
    u16* ao    = vT   + (size_t)BHS * DK;
    u16* wqkv  = ao   + (size_t)BHS * DK;
    u16* wo_bf = wqkv + (size_t)192 * DD;

    convert_w<<<dim3((WQKV_CHUNKS + WO_CHUNKS) / 256), dim3(256), 0, stream>>>(
        wq, wk, wv, wo, wqkv, wo_bf);
    qkv_proj<<<dim3(BHS / 64), dim3(512), 0, stream>>>(x, wqkv, q, k, vT);
    flash_attn<<<dim3(SS / 128, BB * HH), dim3(512), 0, stream>>>(q, k, vT, ao);
    out_proj<<<dim3(DD / 64, (BB * SS) / 64), dim3(256), 0, stream>>>(ao, wo_bf, out);
}

// Round 9
// 526.363 us; speedup vs baseline: 1.4903x; 1.0568x over previous
//
#include <hip/hip_runtime.h>
#include <math.h>

// Shapes (fixed)
#define BB 2
#define HH 16
#define SS 2048
#define DD 1024
#define DK 64
#define BHS (BB*HH*SS)          // 65536
#define QSCALE 0.04508422f      // log2(e)/sqrt(1024): folded into q so softmax uses exp2

typedef short  bf16x8  __attribute__((ext_vector_type(8)));
typedef float  floatx4 __attribute__((ext_vector_type(4)));
typedef unsigned short u16;

#define MFMA(a,b,c) __builtin_amdgcn_mfma_f32_16x16x32_bf16((a),(b),(c),0,0,0)

// hardware packed conversion: dst.lo = bf16(lo), dst.hi = bf16(hi), RNE
__device__ __forceinline__ unsigned cvt_pk_bf16(float lo, float hi) {
    unsigned r;
    asm("v_cvt_pk_bf16_f32 %0, %1, %2" : "=v"(r) : "v"(lo), "v"(hi));
    return r;
}
__device__ __forceinline__ bf16x8 ldfrag(const u16* p) {
    union { uint4 u; bf16x8 b; } c;
    c.u = *(const uint4*)p;
    return c.b;
}
__device__ __forceinline__ void stbf4(u16* p, float4 t) {  // 4xf32 -> 4xbf16, 8B store
    union { unsigned u[2]; uint2 v; } c;
    c.u[0] = cvt_pk_bf16(t.x, t.y);
    c.u[1] = cvt_pk_bf16(t.z, t.w);
    *(uint2*)p = c.v;
}
// 4 f32 -> bf16 at p[0], p[16], p[32], p[48]  (C-fragment col stride 16)
__device__ __forceinline__ void st4s(u16* p, float a, float b, float c, float d) {
    unsigned x = cvt_pk_bf16(a, b), y = cvt_pk_bf16(c, d);
    p[0]  = (u16)x; p[16] = (u16)(x >> 16);
    p[32] = (u16)y; p[48] = (u16)(y >> 16);
}
// 2 f32 -> bf16 at p[0], p[16]
__device__ __forceinline__ void st2s(u16* p, float a, float b) {
    unsigned x = cvt_pk_bf16(a, b);
    p[0]  = (u16)x; p[16] = (u16)(x >> 16);
}

// ---------------------------------------------------------------------------
// Kernel 0: one-shot weight conversion fp32->bf16 (frozen).
// ---------------------------------------------------------------------------
#define WQKV_CHUNKS (192*1024/4)     // 49152 float4 chunks
#define WO_CHUNKS   (1024*1024/4)    // 262144
__global__ __launch_bounds__(256) void convert_w(
    const float* __restrict__ wq, const float* __restrict__ wk,
    const float* __restrict__ wv, const float* __restrict__ wo,
    u16* __restrict__ wqkv, u16* __restrict__ wo_bf)
{
    int i = blockIdx.x * 256 + threadIdx.x;
    if (i < WQKV_CHUNKS) {
        int r = i >> 8;            // row 0..191 (256 float4 per row)
        int c = i & 255;
        const float* src = (r < 64) ? wq : ((r < 128) ? wk : wv);
        float4 t = *(const float4*)(src + (size_t)(r & 63) * DD + c * 4);
        stbf4(wqkv + (size_t)r * DD + c * 4, t);
    } else if (i < WQKV_CHUNKS + WO_CHUNKS) {
        int j = i - WQKV_CHUNKS;
        float4 t = *(const float4*)(wo + (size_t)j * 4);
        stbf4(wo_bf + (size_t)j * 4, t);
    }
}

// ---------------------------------------------------------------------------
// Kernel 1: QKV projection v5 — DRAM-burst X staging.
// Per block (64 rows, 512 thr): 4 K-quarter passes. Each pass stages
// Xq[64][256] where ONE WAVE reads ONE CONTIGUOUS 1 KB row-run per load
// instruction (vs 32-256 B granules at 4 KB stride before -> DRAM page
// thrashing, the suspected cause of the ~150 us / 1.8 TB/s plateau).
// Then 4 k-steps: W[192][64] single-buffered (2 barriers), A from Xq LDS
// (same fragment math as the verified kernel). Epilogue unchanged.
// ---------------------------------------------------------------------------
__global__ __launch_bounds__(512) void qkv_proj(
    const float* __restrict__ x, const u16* __restrict__ wqkv,
    u16* __restrict__ q, u16* __restrict__ k, u16* __restrict__ vT)
{
    __shared__ __align__(16) u16 Xq[64][264];   // 33.8 KB quarter-K X panel
    __shared__ __align__(16) u16 Ws[192][72];   // 27.6 KB W k-slice
    const int tid  = threadIdx.x;
    const int w    = tid >> 6;
    const int lane = tid & 63;
    const int quad = lane >> 4;
    const int l16  = lane & 15;
    const int rt   = w & 3;
    const int g    = w >> 2;
    const int rowbase = blockIdx.x * 64;

    floatx4 acc[6];
#pragma unroll
    for (int j = 0; j < 6; ++j) acc[j] = (floatx4){0.f,0.f,0.f,0.f};

    for (int qd = 0; qd < 4; ++qd) {
        // stage X quarter: 64 rows x 256 cols fp32 -> bf16.
        // it-step: wave w covers row (w + it*8) as 64 lanes x 16 B = 1 KB run.
#pragma unroll
        for (int it = 0; it < 8; ++it) {
            int li = tid + it * 512;
            int r  = li >> 6, c4 = li & 63;
            float4 t = *(const float4*)(x + (size_t)(rowbase + r) * DD
                                          + qd * 256 + c4 * 4);
            stbf4(&Xq[r][c4 * 4], t);
        }
        for (int ks = 0; ks < 4; ++ks) {
            int kk = qd * 4 + ks;
            // stage W k-slice 192x64 (1536 uint4, 3/thread)
#pragma unroll
            for (int it = 0; it < 3; ++it) {
                int li = tid + it * 512;
                int r  = li >> 3, c8 = li & 7;
                *(uint4*)&Ws[r][c8 * 8] =
                    *(const uint4*)(wqkv + (size_t)r * DD + kk * 64 + c8 * 8);
            }
            __syncthreads();    // Xq (ks==0) and Ws visible

            bf16x8 a0 = ldfrag(&Xq[rt * 16 + l16][ks * 64 + quad * 8]);
            bf16x8 a1 = ldfrag(&Xq[rt * 16 + l16][ks * 64 + 32 + quad * 8]);
#pragma unroll
            for (int j = 0; j < 6; ++j) {
                int n = g * 6 + j;
                bf16x8 b0 = ldfrag(&Ws[n * 16 + l16][quad * 8]);
                bf16x8 b1 = ldfrag(&Ws[n * 16 + l16][32 + quad * 8]);
                acc[j] = MFMA(a0, b0, acc[j]);
                acc[j] = MFMA(a1, b1, acc[j]);
            }
            __syncthreads();    // Ws/Xq consumed; safe to restage
        }
    }

    // epilogue: global row = rowbase + rt*16 + quad*4 + rr; col = n*16 + l16
    // (identical to the measured kernel; Vbuf overlays Ws, dead after barrier)
    u16 (*Vbuf)[72] = (u16 (*)[72])&Ws[0][0];
#pragma unroll
    for (int rr = 0; rr < 4; ++rr) {
        int rloc = rt * 16 + quad * 4 + rr;
        size_t m = (size_t)(rowbase + rloc);
        if (g == 0) {
            st4s(&q[m * DK + l16], acc[0][rr] * QSCALE, acc[1][rr] * QSCALE,
                                   acc[2][rr] * QSCALE, acc[3][rr] * QSCALE);
            st2s(&k[m * DK + l16], acc[4][rr], acc[5][rr]);
        } else {
            st2s(&k[m * DK + 32 + l16], acc[0][rr], acc[1][rr]);
            st4s(&Vbuf[rloc][l16], acc[2][rr], acc[3][rr],
                                   acc[4][rr], acc[5][rr]);
        }
    }
    __syncthreads();
    {
        const int dk = tid >> 3;
        const int sc = (tid & 7) * 8;
        const int bh = rowbase >> 11;
        const int s0 = rowbase & 2047;
        union { u16 s[8]; uint4 u; } t;
#pragma unroll
        for (int u = 0; u < 8; ++u) t.s[u] = Vbuf[sc + u][dk];
        *(uint4*)(vT + ((size_t)(bh * DK + dk)) * SS + s0 + sc) = t.u;
    }
}

// ---------------------------------------------------------------------------
// Kernel 2: flash attention v4 (frozen from the 556 us run). QBLK=128 via
// 512 thr / 8 waves; K/V staged once per 128 q-rows; per-wave inner loop =
// measured v1 (KVBLK=64, eager softmax + defer-max, P via LDS, setprio);
// Q fragments in registers.
// ---------------------------------------------------------------------------
__global__ __launch_bounds__(512) void flash_attn(
    const u16* __restrict__ q, const u16* __restrict__ k,
    const u16* __restrict__ vT, u16* __restrict__ ao)
{
    __shared__ __align__(16) u16 Ks[64][72];       //  9.2 KB
    __shared__ __align__(16) u16 Vt[64][72];       //  9.2 KB  Vt[dk][t]
    __shared__ __align__(16) u16 Ps[8][16][72];    // 18.4 KB per-wave P tiles
    const int tid  = threadIdx.x;
    const int w    = tid >> 6;
    const int lane = tid & 63;
    const int quad = lane >> 4;
    const int l16  = lane & 15;
    const int rg   = w >> 2;       // row group (0/1) within 128-row tile
    const int rt   = w & 3;        // row tile within group
    const int qt   = blockIdx.x;   // 0..15
    const int bh   = blockIdx.y;
    const size_t kbase = (size_t)bh * SS * DK;     // q,k layout [bh*S + t][64]
    const size_t vbase = (size_t)bh * DK * SS;     // vT layout [bh*64 + dk][S]

    // Q fragments: invariant over kt -> registers, once
    const u16* qrow = q + kbase +
        (size_t)(qt * 128 + rg * 64 + rt * 16 + l16) * DK;
    const bf16x8 qa0 = ldfrag(qrow + quad * 8);
    const bf16x8 qa1 = ldfrag(qrow + 32 + quad * 8);

    float m_i[4], l_i[4];
    floatx4 acc_o[4];
#pragma unroll
    for (int r = 0; r < 4; ++r) { m_i[r] = -INFINITY; l_i[r] = 0.f; }
#pragma unroll
    for (int n = 0; n < 4; ++n) acc_o[n] = (floatx4){0.f,0.f,0.f,0.f};

    for (int kt = 0; kt < SS / 64; ++kt) {
        // stage K tile [64 t][64 dk] and Vt tile [64 dk][64 t]
        // 512 uint4 chunks each -> exactly 1 K-chunk + 1 V-chunk per thread
        {
            int r  = tid >> 3, c8 = tid & 7;
            *(uint4*)&Ks[r][c8 * 8] =
                *(const uint4*)(k + kbase + (size_t)(kt * 64 + r) * DK + c8 * 8);
            *(uint4*)&Vt[r][c8 * 8] =
                *(const uint4*)(vT + vbase + (size_t)r * SS + kt * 64 + c8 * 8);
        }
        __syncthreads();

        // scores (log2 units)
        floatx4 sc[4];
        __builtin_amdgcn_s_setprio(1);
#pragma unroll
        for (int n = 0; n < 4; ++n) {
            sc[n] = (floatx4){0.f,0.f,0.f,0.f};
            bf16x8 b0 = ldfrag(&Ks[n * 16 + l16][quad * 8]);
            bf16x8 b1 = ldfrag(&Ks[n * 16 + l16][32 + quad * 8]);
            sc[n] = MFMA(qa0, b0, sc[n]);
            sc[n] = MFMA(qa1, b1, sc[n]);
        }
        __builtin_amdgcn_s_setprio(0);

        // row maxima (row = quad*4+r), 16-lane butterfly
        float rmx[4];
#pragma unroll
        for (int r = 0; r < 4; ++r) {
            float rm = fmaxf(fmaxf(sc[0][r], sc[1][r]), fmaxf(sc[2][r], sc[3][r]));
#pragma unroll
            for (int off = 1; off < 16; off <<= 1)
                rm = fmaxf(rm, __shfl_xor(rm, off, 64));
            rmx[r] = rm;
        }
        // defer-max (THR=8 in log2 units)
        int ok = (rmx[0] <= m_i[0] + 8.f) & (rmx[1] <= m_i[1] + 8.f) &
                 (rmx[2] <= m_i[2] + 8.f) & (rmx[3] <= m_i[3] + 8.f);
        if (!__all(ok)) {
#pragma unroll
            for (int r = 0; r < 4; ++r) {
                float mnew  = fmaxf(m_i[r], rmx[r]);
                float alpha = __builtin_amdgcn_exp2f(m_i[r] - mnew);
#pragma unroll
                for (int n = 0; n < 4; ++n) acc_o[n][r] *= alpha;
                l_i[r] *= alpha;
                m_i[r]  = mnew;
            }
        }
        // P = exp2(S - m), row sums, P -> LDS
#pragma unroll
        for (int r = 0; r < 4; ++r) {
            float mi = m_i[r];
            float p0 = __builtin_amdgcn_exp2f(sc[0][r] - mi);
            float p1 = __builtin_amdgcn_exp2f(sc[1][r] - mi);
            float p2 = __builtin_amdgcn_exp2f(sc[2][r] - mi);
            float p3 = __builtin_amdgcn_exp2f(sc[3][r] - mi);
            float rs = (p0 + p1) + (p2 + p3);
#pragma unroll
            for (int off = 1; off < 16; off <<= 1)
                rs += __shfl_xor(rs, off, 64);
            l_i[r] += rs;
            st4s(&Ps[w][quad * 4 + r][l16], p0, p1, p2, p3);
        }
        // Ps per-wave private: no barrier (compiler inserts lgkmcnt)

        // PV
        __builtin_amdgcn_s_setprio(1);
#pragma unroll
        for (int kc = 0; kc < 2; ++kc) {
            bf16x8 a = ldfrag(&Ps[w][l16][kc * 32 + quad * 8]);
#pragma unroll
            for (int n = 0; n < 4; ++n) {
                bf16x8 b = ldfrag(&Vt[n * 16 + l16][kc * 32 + quad * 8]);
                acc_o[n] = MFMA(a, b, acc_o[n]);
            }
        }
        __builtin_amdgcn_s_setprio(0);
        __syncthreads();                            // done reading Ks/Vt
    }

    // epilogue -> ao[B,S,H*64] bf16
    const int b = bh >> 4, h = bh & 15;
#pragma unroll
    for (int r = 0; r < 4; ++r) {
        int srow = qt * 128 + rg * 64 + rt * 16 + quad * 4 + r;
        float rl = __builtin_amdgcn_rcpf(l_i[r]);
        size_t base = ((size_t)(b * SS + srow)) * (HH * DK) + h * 64;
        st4s(&ao[base + l16], acc_o[0][r] * rl, acc_o[1][r] * rl,
                              acc_o[2][r] * rl, acc_o[3][r] * rl);
    }
}

// ---------------------------------------------------------------------------
// Kernel 3: output projection (frozen R3-measured v1: 64x64, 256 thr,
// grid 1024 -> 4 blocks/CU staging overlap).
// ---------------------------------------------------------------------------
__global__ __launch_bounds__(256) void out_proj(
    const u16* __restrict__ ao, const u16* __restrict__ wo_bf,
    float* __restrict__ out)
{
    __shared__ __align__(16) u16 As[64][72];
    __shared__ __align__(16) u16 Bs[64][72];
    const int tid  = threadIdx.x;
    const int w    = tid >> 6;
    const int lane = tid & 63;
    const int quad = lane >> 4;
    const int l16  = lane & 15;
    const int mt = blockIdx.y;
    const int nt = blockIdx.x;

    floatx4 acc[4];
#pragma unroll
    for (int n = 0; n < 4; ++n) acc[n] = (floatx4){0.f,0.f,0.f,0.f};

    for (int k0 = 0; k0 < DD; k0 += 64) {
#pragma unroll
        for (int it = 0; it < 2; ++it) {
            int li = tid + it * 256;
            int r  = li >> 3, c8 = li & 7;
            *(uint4*)&As[r][c8 * 8] =
                *(const uint4*)(ao + (size_t)(mt * 64 + r) * DD + k0 + c8 * 8);
            *(uint4*)&Bs[r][c8 * 8] =
                *(const uint4*)(wo_bf + (size_t)(nt * 64 + r) * DD + k0 + c8 * 8);
        }
        __syncthreads();

        bf16x8 a0 = ldfrag(&As[w * 16 + l16][quad * 8]);
        bf16x8 a1 = ldfrag(&As[w * 16 + l16][32 + quad * 8]);
#pragma unroll
        for (int n = 0; n < 4; ++n) {
            bf16x8 b0 = ldfrag(&Bs[n * 16 + l16][quad * 8]);
            bf16x8 b1 = ldfrag(&Bs[n * 16 + l16][32 + quad * 8]);
            acc[n] = MFMA(a0, b0, acc[n]);
            acc[n] = MFMA(a1, b1, acc[n]);
        }
        __syncthreads();
    }

#pragma unroll
    for (int r = 0; r < 4; ++r) {
        int row = mt * 64 + w * 16 + quad * 4 + r;
#pragma unroll
        for (int n = 0; n < 4; ++n)
            out[(size_t)row * DD + nt * 64 + n * 16 + l16] = acc[n][r];
    }
}

// ---------------------------------------------------------------------------
extern "C" void kernel_launch(void* const* d_in, const int* in_sizes, int n_in,
                              void* d_out, int out_size, void* d_ws, size_t ws_size,
                              hipStream_t stream) {
    const float* x  = (const float*)d_in[0];
    const float* wq = (const float*)d_in[1];
    const float* wk = (const float*)d_in[2];
    const float* wv = (const float*)d_in[3];
    const float* wo = (const float*)d_in[4];
    float* out = (float*)d_out;

    u16* q     = (u16*)d_ws;
    u16* k     = q    + (size_t)BHS * DK;
    u16* vT    = k    + (size_t)BHS * DK;
    u16* ao    = vT   + (size_t)BHS * DK;
    u16* wqkv  = ao   + (size_t)BHS * DK;
    u16* wo_bf = wqkv + (size_t)192 * DD;

    convert_w<<<dim3((WQKV_CHUNKS + WO_CHUNKS) / 256), dim3(256), 0, stream>>>(
        wq, wk, wv, wo, wqkv, wo_bf);
    qkv_proj<<<dim3(BHS / 64), dim3(512), 0, stream>>>(x, wqkv, q, k, vT);
    flash_attn<<<dim3(SS / 128, BB * HH), dim3(512), 0, stream>>>(q, k, vT, ao);
    out_proj<<<dim3(DD / 64, (BB * SS) / 64), dim3(256), 0, stream>>>(ao, wo_bf, out);
}

// Round 10
// 483.455 us; speedup vs baseline: 1.6226x; 1.0888x over previous
//
#include <hip/hip_runtime.h>
#include <math.h>

// Shapes (fixed)
#define BB 2
#define HH 16
#define SS 2048
#define DD 1024
#define DK 64
#define BHS (BB*HH*SS)          // 65536
#define QSCALE 0.04508422f      // log2(e)/sqrt(1024): folded into q so softmax uses exp2

typedef short  bf16x8  __attribute__((ext_vector_type(8)));
typedef float  floatx4 __attribute__((ext_vector_type(4)));
typedef unsigned short u16;

#define MFMA(a,b,c) __builtin_amdgcn_mfma_f32_16x16x32_bf16((a),(b),(c),0,0,0)

// hardware packed conversion: dst.lo = bf16(lo), dst.hi = bf16(hi), RNE
__device__ __forceinline__ unsigned cvt_pk_bf16(float lo, float hi) {
    unsigned r;
    asm("v_cvt_pk_bf16_f32 %0, %1, %2" : "=v"(r) : "v"(lo), "v"(hi));
    return r;
}
__device__ __forceinline__ bf16x8 ldfrag(const u16* p) {
    union { uint4 u; bf16x8 b; } c;
    c.u = *(const uint4*)p;
    return c.b;
}
__device__ __forceinline__ void stbf4(u16* p, float4 t) {  // 4xf32 -> 4xbf16, 8B store
    union { unsigned u[2]; uint2 v; } c;
    c.u[0] = cvt_pk_bf16(t.x, t.y);
    c.u[1] = cvt_pk_bf16(t.z, t.w);
    *(uint2*)p = c.v;
}
// 4 f32 -> bf16 at p[0], p[16], p[32], p[48]  (C-fragment col stride 16)
__device__ __forceinline__ void st4s(u16* p, float a, float b, float c, float d) {
    unsigned x = cvt_pk_bf16(a, b), y = cvt_pk_bf16(c, d);
    p[0]  = (u16)x; p[16] = (u16)(x >> 16);
    p[32] = (u16)y; p[48] = (u16)(y >> 16);
}
// 2 f32 -> bf16 at p[0], p[16]
__device__ __forceinline__ void st2s(u16* p, float a, float b) {
    unsigned x = cvt_pk_bf16(a, b);
    p[0]  = (u16)x; p[16] = (u16)(x >> 16);
}

// ---------------------------------------------------------------------------
// Kernel 0: one-shot weight conversion fp32->bf16 (frozen).
// ---------------------------------------------------------------------------
#define WQKV_CHUNKS (192*1024/4)     // 49152 float4 chunks
#define WO_CHUNKS   (1024*1024/4)    // 262144
__global__ __launch_bounds__(256) void convert_w(
    const float* __restrict__ wq, const float* __restrict__ wk,
    const float* __restrict__ wv, const float* __restrict__ wo,
    u16* __restrict__ wqkv, u16* __restrict__ wo_bf)
{
    int i = blockIdx.x * 256 + threadIdx.x;
    if (i < WQKV_CHUNKS) {
        int r = i >> 8;            // row 0..191 (256 float4 per row)
        int c = i & 255;
        const float* src = (r < 64) ? wq : ((r < 128) ? wk : wv);
        float4 t = *(const float4*)(src + (size_t)(r & 63) * DD + c * 4);
        stbf4(wqkv + (size_t)r * DD + c * 4, t);
    } else if (i < WQKV_CHUNKS + WO_CHUNKS) {
        int j = i - WQKV_CHUNKS;
        float4 t = *(const float4*)(wo + (size_t)j * 4);
        stbf4(wo_bf + (size_t)j * 4, t);
    }
}

// ---------------------------------------------------------------------------
// Kernel 1: QKV projection v5 — DRAM-burst X staging (frozen from 526 us run).
// ---------------------------------------------------------------------------
__global__ __launch_bounds__(512) void qkv_proj(
    const float* __restrict__ x, const u16* __restrict__ wqkv,
    u16* __restrict__ q, u16* __restrict__ k, u16* __restrict__ vT)
{
    __shared__ __align__(16) u16 Xq[64][264];   // 33.8 KB quarter-K X panel
    __shared__ __align__(16) u16 Ws[192][72];   // 27.6 KB W k-slice
    const int tid  = threadIdx.x;
    const int w    = tid >> 6;
    const int lane = tid & 63;
    const int quad = lane >> 4;
    const int l16  = lane & 15;
    const int rt   = w & 3;
    const int g    = w >> 2;
    const int rowbase = blockIdx.x * 64;

    floatx4 acc[6];
#pragma unroll
    for (int j = 0; j < 6; ++j) acc[j] = (floatx4){0.f,0.f,0.f,0.f};

    for (int qd = 0; qd < 4; ++qd) {
        // stage X quarter: 64 rows x 256 cols fp32 -> bf16 (1 KB row-runs)
#pragma unroll
        for (int it = 0; it < 8; ++it) {
            int li = tid + it * 512;
            int r  = li >> 6, c4 = li & 63;
            float4 t = *(const float4*)(x + (size_t)(rowbase + r) * DD
                                          + qd * 256 + c4 * 4);
            stbf4(&Xq[r][c4 * 4], t);
        }
        for (int ks = 0; ks < 4; ++ks) {
            int kk = qd * 4 + ks;
            // stage W k-slice 192x64 (1536 uint4, 3/thread)
#pragma unroll
            for (int it = 0; it < 3; ++it) {
                int li = tid + it * 512;
                int r  = li >> 3, c8 = li & 7;
                *(uint4*)&Ws[r][c8 * 8] =
                    *(const uint4*)(wqkv + (size_t)r * DD + kk * 64 + c8 * 8);
            }
            __syncthreads();    // Xq (ks==0) and Ws visible

            bf16x8 a0 = ldfrag(&Xq[rt * 16 + l16][ks * 64 + quad * 8]);
            bf16x8 a1 = ldfrag(&Xq[rt * 16 + l16][ks * 64 + 32 + quad * 8]);
#pragma unroll
            for (int j = 0; j < 6; ++j) {
                int n = g * 6 + j;
                bf16x8 b0 = ldfrag(&Ws[n * 16 + l16][quad * 8]);
                bf16x8 b1 = ldfrag(&Ws[n * 16 + l16][32 + quad * 8]);
                acc[j] = MFMA(a0, b0, acc[j]);
                acc[j] = MFMA(a1, b1, acc[j]);
            }
            __syncthreads();    // Ws/Xq consumed; safe to restage
        }
    }

    // epilogue (identical to measured kernel; Vbuf overlays Ws)
    u16 (*Vbuf)[72] = (u16 (*)[72])&Ws[0][0];
#pragma unroll
    for (int rr = 0; rr < 4; ++rr) {
        int rloc = rt * 16 + quad * 4 + rr;
        size_t m = (size_t)(rowbase + rloc);
        if (g == 0) {
            st4s(&q[m * DK + l16], acc[0][rr] * QSCALE, acc[1][rr] * QSCALE,
                                   acc[2][rr] * QSCALE, acc[3][rr] * QSCALE);
            st2s(&k[m * DK + l16], acc[4][rr], acc[5][rr]);
        } else {
            st2s(&k[m * DK + 32 + l16], acc[0][rr], acc[1][rr]);
            st4s(&Vbuf[rloc][l16], acc[2][rr], acc[3][rr],
                                   acc[4][rr], acc[5][rr]);
        }
    }
    __syncthreads();
    {
        const int dk = tid >> 3;
        const int sc = (tid & 7) * 8;
        const int bh = rowbase >> 11;
        const int s0 = rowbase & 2047;
        union { u16 s[8]; uint4 u; } t;
#pragma unroll
        for (int u = 0; u < 8; ++u) t.s[u] = Vbuf[sc + u][dk];
        *(uint4*)(vT + ((size_t)(bh * DK + dk)) * SS + s0 + sc) = t.u;
    }
}

// ---------------------------------------------------------------------------
// Kernel 2: flash attention v5. v4 structure (QBLK=128, 512 thr, 8 waves,
// KVBLK=64, K/V staged once per 128 q-rows, Q in regs, P via LDS, setprio)
// + lazy softmax grafted from the harness-verified v3: lane-local defer-max
// check (no shuffles in common path) and per-lane partial row sums with a
// single epilogue butterfly. Removes ~32 ds_swizzle ops per iter per wave
// (the largest removable DS-pipe term).
// ---------------------------------------------------------------------------
__global__ __launch_bounds__(512) void flash_attn(
    const u16* __restrict__ q, const u16* __restrict__ k,
    const u16* __restrict__ vT, u16* __restrict__ ao)
{
    __shared__ __align__(16) u16 Ks[64][72];       //  9.2 KB
    __shared__ __align__(16) u16 Vt[64][72];       //  9.2 KB  Vt[dk][t]
    __shared__ __align__(16) u16 Ps[8][16][72];    // 18.4 KB per-wave P tiles
    const int tid  = threadIdx.x;
    const int w    = tid >> 6;
    const int lane = tid & 63;
    const int quad = lane >> 4;
    const int l16  = lane & 15;
    const int rg   = w >> 2;       // row group (0/1) within 128-row tile
    const int rt   = w & 3;        // row tile within group
    const int qt   = blockIdx.x;   // 0..15
    const int bh   = blockIdx.y;
    const size_t kbase = (size_t)bh * SS * DK;     // q,k layout [bh*S + t][64]
    const size_t vbase = (size_t)bh * DK * SS;     // vT layout [bh*64 + dk][S]

    // Q fragments: invariant over kt -> registers, once
    const u16* qrow = q + kbase +
        (size_t)(qt * 128 + rg * 64 + rt * 16 + l16) * DK;
    const bf16x8 qa0 = ldfrag(qrow + quad * 8);
    const bf16x8 qa1 = ldfrag(qrow + 32 + quad * 8);

    float m_i[4], l_part[4];
    floatx4 acc_o[4];
#pragma unroll
    for (int r = 0; r < 4; ++r) { m_i[r] = -INFINITY; l_part[r] = 0.f; }
#pragma unroll
    for (int n = 0; n < 4; ++n) acc_o[n] = (floatx4){0.f,0.f,0.f,0.f};

    for (int kt = 0; kt < SS / 64; ++kt) {
        // stage K tile [64 t][64 dk] and Vt tile [64 dk][64 t]
        {
            int r  = tid >> 3, c8 = tid & 7;
            *(uint4*)&Ks[r][c8 * 8] =
                *(const uint4*)(k + kbase + (size_t)(kt * 64 + r) * DK + c8 * 8);
            *(uint4*)&Vt[r][c8 * 8] =
                *(const uint4*)(vT + vbase + (size_t)r * SS + kt * 64 + c8 * 8);
        }
        __syncthreads();

        // scores (log2 units)
        floatx4 sc[4];
        __builtin_amdgcn_s_setprio(1);
#pragma unroll
        for (int n = 0; n < 4; ++n) {
            sc[n] = (floatx4){0.f,0.f,0.f,0.f};
            bf16x8 b0 = ldfrag(&Ks[n * 16 + l16][quad * 8]);
            bf16x8 b1 = ldfrag(&Ks[n * 16 + l16][32 + quad * 8]);
            sc[n] = MFMA(qa0, b0, sc[n]);
            sc[n] = MFMA(qa1, b1, sc[n]);
        }
        __builtin_amdgcn_s_setprio(0);

        // lane-local defer-max check (row max <= m+8  <=>  all lanes' lm <= m+8)
        float lm[4];
#pragma unroll
        for (int r = 0; r < 4; ++r)
            lm[r] = fmaxf(fmaxf(sc[0][r], sc[1][r]), fmaxf(sc[2][r], sc[3][r]));
        int ok = (lm[0] <= m_i[0] + 8.f) & (lm[1] <= m_i[1] + 8.f) &
                 (lm[2] <= m_i[2] + 8.f) & (lm[3] <= m_i[3] + 8.f);
        if (!__all(ok)) {          // rare: true row max via butterfly + rescale
#pragma unroll
            for (int r = 0; r < 4; ++r) {
                float rm = lm[r];
#pragma unroll
                for (int off = 1; off < 16; off <<= 1)
                    rm = fmaxf(rm, __shfl_xor(rm, off, 64));
                float mnew  = fmaxf(m_i[r], rm);
                float alpha = __builtin_amdgcn_exp2f(m_i[r] - mnew);
#pragma unroll
                for (int n = 0; n < 4; ++n) acc_o[n][r] *= alpha;
                l_part[r] *= alpha;
                m_i[r]     = mnew;
            }
        }
        // P = exp2(S - m); per-lane partial row sums (no shuffles); P -> LDS
#pragma unroll
        for (int r = 0; r < 4; ++r) {
            float mi = m_i[r];
            float p0 = __builtin_amdgcn_exp2f(sc[0][r] - mi);
            float p1 = __builtin_amdgcn_exp2f(sc[1][r] - mi);
            float p2 = __builtin_amdgcn_exp2f(sc[2][r] - mi);
            float p3 = __builtin_amdgcn_exp2f(sc[3][r] - mi);
            l_part[r] += (p0 + p1) + (p2 + p3);
            st4s(&Ps[w][quad * 4 + r][l16], p0, p1, p2, p3);
        }
        // Ps per-wave private: no barrier (compiler inserts lgkmcnt)

        // PV
        __builtin_amdgcn_s_setprio(1);
#pragma unroll
        for (int kc = 0; kc < 2; ++kc) {
            bf16x8 a = ldfrag(&Ps[w][l16][kc * 32 + quad * 8]);
#pragma unroll
            for (int n = 0; n < 4; ++n) {
                bf16x8 b = ldfrag(&Vt[n * 16 + l16][kc * 32 + quad * 8]);
                acc_o[n] = MFMA(a, b, acc_o[n]);
            }
        }
        __builtin_amdgcn_s_setprio(0);
        __syncthreads();                            // done reading Ks/Vt
    }

    // epilogue: single butterfly for the row sums, then -> ao[B,S,H*64] bf16
    const int b = bh >> 4, h = bh & 15;
#pragma unroll
    for (int r = 0; r < 4; ++r) {
        float l = l_part[r];
#pragma unroll
        for (int off = 1; off < 16; off <<= 1)
            l += __shfl_xor(l, off, 64);
        float rl = __builtin_amdgcn_rcpf(l);
        int srow = qt * 128 + rg * 64 + rt * 16 + quad * 4 + r;
        size_t base = ((size_t)(b * SS + srow)) * (HH * DK) + h * 64;
        st4s(&ao[base + l16], acc_o[0][r] * rl, acc_o[1][r] * rl,
                              acc_o[2][r] * rl, acc_o[3][r] * rl);
    }
}

// ---------------------------------------------------------------------------
// Kernel 3: output projection (frozen R3-measured v1: 64x64, 256 thr,
// grid 1024 -> 4 blocks/CU staging overlap).
// ---------------------------------------------------------------------------
__global__ __launch_bounds__(256) void out_proj(
    const u16* __restrict__ ao, const u16* __restrict__ wo_bf,
    float* __restrict__ out)
{
    __shared__ __align__(16) u16 As[64][72];
    __shared__ __align__(16) u16 Bs[64][72];
    const int tid  = threadIdx.x;
    const int w    = tid >> 6;
    const int lane = tid & 63;
    const int quad = lane >> 4;
    const int l16  = lane & 15;
    const int mt = blockIdx.y;
    const int nt = blockIdx.x;

    floatx4 acc[4];
#pragma unroll
    for (int n = 0; n < 4; ++n) acc[n] = (floatx4){0.f,0.f,0.f,0.f};

    for (int k0 = 0; k0 < DD; k0 += 64) {
#pragma unroll
        for (int it = 0; it < 2; ++it) {
            int li = tid + it * 256;
            int r  = li >> 3, c8 = li & 7;
            *(uint4*)&As[r][c8 * 8] =
                *(const uint4*)(ao + (size_t)(mt * 64 + r) * DD + k0 + c8 * 8);
            *(uint4*)&Bs[r][c8 * 8] =
                *(const uint4*)(wo_bf + (size_t)(nt * 64 + r) * DD + k0 + c8 * 8);
        }
        __syncthreads();

        bf16x8 a0 = ldfrag(&As[w * 16 + l16][quad * 8]);
        bf16x8 a1 = ldfrag(&As[w * 16 + l16][32 + quad * 8]);
#pragma unroll
        for (int n = 0; n < 4; ++n) {
            bf16x8 b0 = ldfrag(&Bs[n * 16 + l16][quad * 8]);
            bf16x8 b1 = ldfrag(&Bs[n * 16 + l16][32 + quad * 8]);
            acc[n] = MFMA(a0, b0, acc[n]);
            acc[n] = MFMA(a1, b1, acc[n]);
        }
        __syncthreads();
    }

#pragma unroll
    for (int r = 0; r < 4; ++r) {
        int row = mt * 64 + w * 16 + quad * 4 + r;
#pragma unroll
        for (int n = 0; n < 4; ++n)
            out[(size_t)row * DD + nt * 64 + n * 16 + l16] = acc[n][r];
    }
}

// ---------------------------------------------------------------------------
extern "C" void kernel_launch(void* const* d_in, const int* in_sizes, int n_in,
                              void* d_out, int out_size, void* d_ws, size_t ws_size,
                              hipStream_t stream) {
    const float* x  = (const float*)d_in[0];
    const float* wq = (const float*)d_in[1];
    const float* wk = (const float*)d_in[2];
    const float* wv = (const float*)d_in[3];
    const float* wo = (const float*)d_in[4];
    float* out = (float*)d_out;

    u16* q     = (u16*)d_ws;
    u16* k     = q    + (size_t)BHS * DK;
    u16* vT    = k    + (size_t)BHS * DK;
    u16* ao    = vT   + (size_t)BHS * DK;
    u16* wqkv  = ao   + (size_t)BHS * DK;
    u16* wo_bf = wqkv + (size_t)192 * DD;

    convert_w<<<dim3((WQKV_CHUNKS + WO_CHUNKS) / 256), dim3(256), 0, stream>>>(
        wq, wk, wv, wo, wqkv, wo_bf);
    qkv_proj<<<dim3(BHS / 64), dim3(512), 0, stream>>>(x, wqkv, q, k, vT);
    flash_attn<<<dim3(SS / 128, BB * HH), dim3(512), 0, stream>>>(q, k, vT, ao);
    out_proj<<<dim3(DD / 64, (BB * SS) / 64), dim3(256), 0, stream>>>(ao, wo_bf, out);
}